// Round 1
// baseline (329.660 us; speedup 1.0000x reference)
//
#include <hip/hip_runtime.h>

#define NN 50000
#define NE 800000
#define IN_DIM 128
#define OUT_DIM 64
#define NEG 0.2f

// ---------------- Kernel A: h = x@W, a_src = h@att_src, a_dst = h@att_dst ---
// 64 rows x 64 cols per block, 256 threads, 4x4 register tile per thread.
__global__ __launch_bounds__(256) void gat_gemm(
    const float* __restrict__ x, const float* __restrict__ W,
    const float* __restrict__ att_src, const float* __restrict__ att_dst,
    float* __restrict__ h, float* __restrict__ a_src, float* __restrict__ a_dst)
{
    __shared__ float xs[64 * 132];   // padded stride 132 to dodge bank conflicts
    __shared__ float Ws[128 * 64];
    const int tid = threadIdx.x;
    const int block_row = blockIdx.x * 64;

    // stage x tile (64 rows x 128) as float4
    for (int t = tid; t < 64 * 32; t += 256) {
        int r = t >> 5, kv = (t & 31) << 2;
        int row = block_row + r;
        float4 v = make_float4(0.f, 0.f, 0.f, 0.f);
        if (row < NN) v = *(const float4*)(x + (size_t)row * IN_DIM + kv);
        *(float4*)(&xs[r * 132 + kv]) = v;
    }
    // stage W (128 x 64)
    for (int t = tid; t < 128 * 16; t += 256) {
        int k = t >> 4, cv = (t & 15) << 2;
        *(float4*)(&Ws[k * 64 + cv]) = *(const float4*)(W + k * 64 + cv);
    }
    __syncthreads();

    const int tx = tid & 15, ty = tid >> 4;
    const int r0 = ty * 4, c0 = tx * 4;
    float acc[4][4] = {};

    for (int kk = 0; kk < 128; kk += 4) {
        float4 xv[4], wv[4];
#pragma unroll
        for (int i = 0; i < 4; ++i) xv[i] = *(float4*)(&xs[(r0 + i) * 132 + kk]);
#pragma unroll
        for (int t = 0; t < 4; ++t) wv[t] = *(float4*)(&Ws[(kk + t) * 64 + c0]);
#pragma unroll
        for (int i = 0; i < 4; ++i) {
            float xa0 = xv[i].x, xa1 = xv[i].y, xa2 = xv[i].z, xa3 = xv[i].w;
            acc[i][0] += xa0 * wv[0].x + xa1 * wv[1].x + xa2 * wv[2].x + xa3 * wv[3].x;
            acc[i][1] += xa0 * wv[0].y + xa1 * wv[1].y + xa2 * wv[2].y + xa3 * wv[3].y;
            acc[i][2] += xa0 * wv[0].z + xa1 * wv[1].z + xa2 * wv[2].z + xa3 * wv[3].z;
            acc[i][3] += xa0 * wv[0].w + xa1 * wv[1].w + xa2 * wv[2].w + xa3 * wv[3].w;
        }
    }

    // epilogue: store h, reduce attention logits across the 16 tx lanes
    float as0 = att_src[c0], as1 = att_src[c0 + 1], as2 = att_src[c0 + 2], as3 = att_src[c0 + 3];
    float ad0 = att_dst[c0], ad1 = att_dst[c0 + 1], ad2 = att_dst[c0 + 2], ad3 = att_dst[c0 + 3];
#pragma unroll
    for (int i = 0; i < 4; ++i) {
        int row = block_row + r0 + i;
        float ps = acc[i][0] * as0 + acc[i][1] * as1 + acc[i][2] * as2 + acc[i][3] * as3;
        float pd = acc[i][0] * ad0 + acc[i][1] * ad1 + acc[i][2] * ad2 + acc[i][3] * ad3;
#pragma unroll
        for (int off = 1; off < 16; off <<= 1) {
            ps += __shfl_xor(ps, off, 64);
            pd += __shfl_xor(pd, off, 64);
        }
        if (row < NN) {
            *(float4*)(&h[(size_t)row * OUT_DIM + c0]) =
                make_float4(acc[i][0], acc[i][1], acc[i][2], acc[i][3]);
            if (tx == 0) { a_src[row] = ps; a_dst[row] = pd; }
        }
    }
}

// ---------------- Kernel B: one wave per edge, scatter num/denom ------------
__global__ __launch_bounds__(256) void gat_edge(
    const int* __restrict__ src, const int* __restrict__ dst,
    const float* __restrict__ a_src, const float* __restrict__ a_dst,
    const float* __restrict__ h,
    float* __restrict__ num, float* __restrict__ denom)
{
    const int e = blockIdx.x * 4 + (threadIdx.x >> 6);
    const int lane = threadIdx.x & 63;
    if (e >= NE) return;
    const int s = src[e];
    const int d = dst[e];
    float v = a_src[s] + a_dst[d];
    v = v > 0.f ? v : NEG * v;
    const float ex = __expf(v);
    const float hv = h[(size_t)s * OUT_DIM + lane];
    atomicAdd(&num[(size_t)d * OUT_DIM + lane], ex * hv);
    if (lane == 0) atomicAdd(&denom[d], ex);
}

// ---------------- Kernel C: finalize with self-loop term --------------------
__global__ __launch_bounds__(256) void gat_final(
    const float* __restrict__ h, const float* __restrict__ a_src,
    const float* __restrict__ a_dst, const float* __restrict__ denom,
    const float* __restrict__ bias, float* __restrict__ out)
{
    const int gid = blockIdx.x * 256 + threadIdx.x;
    if (gid >= NN * OUT_DIM) return;
    const int i = gid >> 6, c = gid & 63;
    float v = a_src[i] + a_dst[i];
    v = v > 0.f ? v : NEG * v;
    const float exs = __expf(v);
    const float numv = out[gid] + exs * h[gid];
    const float den = denom[i] + exs;
    out[gid] = numv / den + bias[c];
}

extern "C" void kernel_launch(void* const* d_in, const int* in_sizes, int n_in,
                              void* d_out, int out_size, void* d_ws, size_t ws_size,
                              hipStream_t stream) {
    const float* x       = (const float*)d_in[0];
    const int*   eidx    = (const int*)d_in[1];   // [2, NE] row-major
    const float* W       = (const float*)d_in[2];
    const float* att_src = (const float*)d_in[3];
    const float* att_dst = (const float*)d_in[4];
    const float* bias    = (const float*)d_in[5];
    float* out = (float*)d_out;

    // workspace layout: h [NN*64] | a_src [NN] | a_dst [NN] | denom [NN]
    float* h     = (float*)d_ws;
    float* a_src = h + (size_t)NN * OUT_DIM;
    float* a_dst = a_src + NN;
    float* denom = a_dst + NN;

    const int* src = eidx;
    const int* dst = eidx + NE;

    // num accumulates directly in d_out -> zero it; zero denom
    hipMemsetAsync(d_out, 0, (size_t)NN * OUT_DIM * sizeof(float), stream);
    hipMemsetAsync(denom, 0, (size_t)NN * sizeof(float), stream);

    gat_gemm<<<(NN + 63) / 64, 256, 0, stream>>>(x, W, att_src, att_dst, h, a_src, a_dst);
    gat_edge<<<(NE + 3) / 4, 256, 0, stream>>>(src, dst, a_src, a_dst, h, out, denom);
    gat_final<<<(NN * OUT_DIM + 255) / 256, 256, 0, stream>>>(h, a_src, a_dst, denom, bias, out);
}

// Round 2
// 262.571 us; speedup vs baseline: 1.2555x; 1.2555x over previous
//
#include <hip/hip_runtime.h>

#define NN 50000
#define NE 800000
#define IN_DIM 128
#define OUT_DIM 64
#define NEG 0.2f

// ---------------- Kernel A: h = x@W, a_src = h@att_src, a_dst = h@att_dst ---
// 64 rows x 64 cols per block, 256 threads, 4x4 register tile per thread.
__global__ __launch_bounds__(256) void gat_gemm(
    const float* __restrict__ x, const float* __restrict__ W,
    const float* __restrict__ att_src, const float* __restrict__ att_dst,
    float* __restrict__ h, float* __restrict__ a_src, float* __restrict__ a_dst)
{
    __shared__ float xs[64 * 132];   // padded stride 132 to dodge bank conflicts
    __shared__ float Ws[128 * 64];
    const int tid = threadIdx.x;
    const int block_row = blockIdx.x * 64;

    for (int t = tid; t < 64 * 32; t += 256) {
        int r = t >> 5, kv = (t & 31) << 2;
        int row = block_row + r;
        float4 v = make_float4(0.f, 0.f, 0.f, 0.f);
        if (row < NN) v = *(const float4*)(x + (size_t)row * IN_DIM + kv);
        *(float4*)(&xs[r * 132 + kv]) = v;
    }
    for (int t = tid; t < 128 * 16; t += 256) {
        int k = t >> 4, cv = (t & 15) << 2;
        *(float4*)(&Ws[k * 64 + cv]) = *(const float4*)(W + k * 64 + cv);
    }
    __syncthreads();

    const int tx = tid & 15, ty = tid >> 4;
    const int r0 = ty * 4, c0 = tx * 4;
    float acc[4][4] = {};

    for (int kk = 0; kk < 128; kk += 4) {
        float4 xv[4], wv[4];
#pragma unroll
        for (int i = 0; i < 4; ++i) xv[i] = *(float4*)(&xs[(r0 + i) * 132 + kk]);
#pragma unroll
        for (int t = 0; t < 4; ++t) wv[t] = *(float4*)(&Ws[(kk + t) * 64 + c0]);
#pragma unroll
        for (int i = 0; i < 4; ++i) {
            float xa0 = xv[i].x, xa1 = xv[i].y, xa2 = xv[i].z, xa3 = xv[i].w;
            acc[i][0] += xa0 * wv[0].x + xa1 * wv[1].x + xa2 * wv[2].x + xa3 * wv[3].x;
            acc[i][1] += xa0 * wv[0].y + xa1 * wv[1].y + xa2 * wv[2].y + xa3 * wv[3].y;
            acc[i][2] += xa0 * wv[0].z + xa1 * wv[1].z + xa2 * wv[2].z + xa3 * wv[3].z;
            acc[i][3] += xa0 * wv[0].w + xa1 * wv[1].w + xa2 * wv[2].w + xa3 * wv[3].w;
        }
    }

    float as0 = att_src[c0], as1 = att_src[c0 + 1], as2 = att_src[c0 + 2], as3 = att_src[c0 + 3];
    float ad0 = att_dst[c0], ad1 = att_dst[c0 + 1], ad2 = att_dst[c0 + 2], ad3 = att_dst[c0 + 3];
#pragma unroll
    for (int i = 0; i < 4; ++i) {
        int row = block_row + r0 + i;
        float ps = acc[i][0] * as0 + acc[i][1] * as1 + acc[i][2] * as2 + acc[i][3] * as3;
        float pd = acc[i][0] * ad0 + acc[i][1] * ad1 + acc[i][2] * ad2 + acc[i][3] * ad3;
#pragma unroll
        for (int off = 1; off < 16; off <<= 1) {
            ps += __shfl_xor(ps, off, 64);
            pd += __shfl_xor(pd, off, 64);
        }
        if (row < NN) {
            *(float4*)(&h[(size_t)row * OUT_DIM + c0]) =
                make_float4(acc[i][0], acc[i][1], acc[i][2], acc[i][3]);
            if (tx == 0) { a_src[row] = ps; a_dst[row] = pd; }
        }
    }
}

// ---------------- Kernel B1: histogram of dst ------------------------------
__global__ __launch_bounds__(256) void gat_hist(
    const int* __restrict__ dst, int* __restrict__ counts)
{
    int e = blockIdx.x * 256 + threadIdx.x;
    if (e < NE) atomicAdd(&counts[dst[e]], 1);
}

// ---------------- Kernel B2: single-block exclusive scan --------------------
__global__ __launch_bounds__(1024) void gat_scan(
    const int* __restrict__ counts, int* __restrict__ row_start,
    int* __restrict__ cursor)
{
    __shared__ int wsum[16];
    __shared__ int carry_s;
    const int tid = threadIdx.x, lane = tid & 63, wid = tid >> 6;
    if (tid == 0) carry_s = 0;
    __syncthreads();

    for (int base = 0; base < NN; base += 1024) {
        const int carry = carry_s;
        const int idx = base + tid;
        const int v = (idx < NN) ? counts[idx] : 0;
        int incl = v;
#pragma unroll
        for (int off = 1; off < 64; off <<= 1) {
            int n = __shfl_up(incl, off, 64);
            if (lane >= off) incl += n;
        }
        if (lane == 63) wsum[wid] = incl;
        __syncthreads();
        int wprefix = 0, total = 0;
#pragma unroll
        for (int w = 0; w < 16; ++w) {
            int s = wsum[w];
            if (w < wid) wprefix += s;
            total += s;
        }
        const int excl = carry + wprefix + incl - v;
        if (idx < NN) { row_start[idx] = excl; cursor[idx] = excl; }
        __syncthreads();
        if (tid == 0) carry_s = carry + total;
        __syncthreads();
    }
    if (tid == 0) row_start[NN] = carry_s;
}

// ---------------- Kernel B3: scatter edges into dst-sorted order ------------
// entry = {src, bits(exp(leaky(a_src[s]+a_dst[d])))}
__global__ __launch_bounds__(256) void gat_scatter(
    const int* __restrict__ src, const int* __restrict__ dst,
    const float* __restrict__ a_src, const float* __restrict__ a_dst,
    int* __restrict__ cursor, int2* __restrict__ entries)
{
    int e = blockIdx.x * 256 + threadIdx.x;
    if (e >= NE) return;
    const int s = src[e];
    const int d = dst[e];
    float v = a_src[s] + a_dst[d];
    v = v > 0.f ? v : NEG * v;
    const float ex = __expf(v);
    const int pos = atomicAdd(&cursor[d], 1);
    entries[pos] = make_int2(s, __float_as_int(ex));
}

// ---------------- Kernel C: per-node gather aggregation ---------------------
// One wave per node. Lane layout: 4 edge-slots (grp) x 16 column-quads (cl).
__global__ __launch_bounds__(256) void gat_agg(
    const int2* __restrict__ entries, const int* __restrict__ row_start,
    const float* __restrict__ h, const float* __restrict__ a_src,
    const float* __restrict__ a_dst, const float* __restrict__ bias,
    float* __restrict__ out)
{
    const int node = blockIdx.x * 4 + (threadIdx.x >> 6);
    if (node >= NN) return;
    const int lane = threadIdx.x & 63;
    const int grp = lane >> 4;      // edge slot 0..3
    const int cl = lane & 15;       // float4 column index

    const int start = row_start[node];
    const int end = row_start[node + 1];

    // self loop term (only group 0 contributes; groups are summed at the end)
    float v = a_src[node] + a_dst[node];
    v = v > 0.f ? v : NEG * v;
    const float exs = __expf(v);
    const float w0 = (grp == 0) ? exs : 0.f;
    float4 hv = *(const float4*)(h + (size_t)node * OUT_DIM + cl * 4);
    float4 acc = make_float4(w0 * hv.x, w0 * hv.y, w0 * hv.z, w0 * hv.w);
    float den = w0;

    for (int base = start; base < end; base += 4) {
        const int e = base + grp;
        if (e < end) {
            const int2 ent = entries[e];          // 16-lane broadcast load
            const int s = ent.x;
            const float ex = __int_as_float(ent.y);
            const float4 hg = *(const float4*)(h + (size_t)s * OUT_DIM + cl * 4);
            acc.x += ex * hg.x; acc.y += ex * hg.y;
            acc.z += ex * hg.z; acc.w += ex * hg.w;
            den += ex;
        }
    }

    // reduce the 4 edge-slot groups (xor over lane bits 16 and 32)
#pragma unroll
    for (int off = 16; off < 64; off <<= 1) {
        acc.x += __shfl_xor(acc.x, off, 64);
        acc.y += __shfl_xor(acc.y, off, 64);
        acc.z += __shfl_xor(acc.z, off, 64);
        acc.w += __shfl_xor(acc.w, off, 64);
        den += __shfl_xor(den, off, 64);
    }

    if (grp == 0) {
        const float4 b = *(const float4*)(bias + cl * 4);
        const float inv = 1.f / den;
        float4 o;
        o.x = acc.x * inv + b.x;
        o.y = acc.y * inv + b.y;
        o.z = acc.z * inv + b.z;
        o.w = acc.w * inv + b.w;
        *(float4*)(out + (size_t)node * OUT_DIM + cl * 4) = o;
    }
}

extern "C" void kernel_launch(void* const* d_in, const int* in_sizes, int n_in,
                              void* d_out, int out_size, void* d_ws, size_t ws_size,
                              hipStream_t stream) {
    const float* x       = (const float*)d_in[0];
    const int*   eidx    = (const int*)d_in[1];   // [2, NE] row-major
    const float* W       = (const float*)d_in[2];
    const float* att_src = (const float*)d_in[3];
    const float* att_dst = (const float*)d_in[4];
    const float* bias    = (const float*)d_in[5];
    float* out = (float*)d_out;

    // workspace layout (floats):
    // h [NN*64] | entries [NE int2] | a_src [NN] | a_dst [NN]
    // | counts [NN] | row_start [NN+1] | cursor [NN]
    float* h       = (float*)d_ws;
    int2*  entries = (int2*)(h + (size_t)NN * OUT_DIM);      // byte off 12.8e6, 8B aligned
    float* a_src   = (float*)(entries + NE);
    float* a_dst   = a_src + NN;
    int*   counts  = (int*)(a_dst + NN);
    int*   row_start = counts + NN;
    int*   cursor  = row_start + NN + 1;

    const int* src = eidx;
    const int* dst = eidx + NE;

    hipMemsetAsync(counts, 0, (size_t)NN * sizeof(int), stream);

    gat_gemm<<<(NN + 63) / 64, 256, 0, stream>>>(x, W, att_src, att_dst, h, a_src, a_dst);
    gat_hist<<<(NE + 255) / 256, 256, 0, stream>>>(dst, counts);
    gat_scan<<<1, 1024, 0, stream>>>(counts, row_start, cursor);
    gat_scatter<<<(NE + 255) / 256, 256, 0, stream>>>(src, dst, a_src, a_dst, cursor, entries);
    gat_agg<<<(NN + 3) / 4, 256, 0, stream>>>(entries, row_start, h, a_src, a_dst, bias, out);
}